// Round 5
// baseline (114.922 us; speedup 1.0000x reference)
//
#include <hip/hip_runtime.h>
#include <hip/hip_fp16.h>

#define N_NODES  100000
#define N_EDGES  1600000
#define N_GRAPHS 64
#define NBUCK    391                 // ceil(N_NODES / 256)
#define NBLK     256
#define CHUNK    (N_EDGES / NBLK)    // 6250 exactly
#define NODEBLK  1563                // ceil(N_NODES / 64)

// ---- workspace layout (int elements). q planes overlay the sort scratch,
// which is dead after k_fine. Max extent 3,802,112 ints = 15.2 MB.
#define OFF_GSTART 0            // 65   -> pad 128
#define OFF_ROWPTR 128          // 100,001 -> pad 100,096
#define OFF_DIS    100224       // 100,000 -> pad 100,096
#define OFF_S      200320       // 200,000 (float2 aligned) -> pad 200,064
#define OFF_CSR    400384       // 1,600,000
#define OFF_QLO    2000384      // 800,000 ints (100k x 8 half2) -> pad 800,128
#define OFF_QHI    2800512      // 800,000 ints
#define OFF_BHIST  2000384      // overlays QLO (dead after k_scan_a)
#define OFF_BOFFL  2100736      // 100,352
#define OFF_BSUM   2201088      // 391 -> pad 512
#define OFF_BSTART 2201600      // 392 -> pad 512
#define OFF_TMP    2202112      // 1,600,000 (dead after k_fine)

// ---------- scan helpers (block-uniform call sites only) ----------
__device__ __forceinline__ int excl_scan_256(int v, int* wsum) {
  int t = threadIdx.x, lane = t & 63, w = t >> 6;
  int x = v;
#pragma unroll
  for (int off = 1; off < 64; off <<= 1) {
    int y = __shfl_up(x, off, 64);
    if (lane >= off) x += y;
  }
  if (lane == 63) wsum[w] = x;
  __syncthreads();
  if (t == 0) {
    int r = 0;
#pragma unroll
    for (int i = 0; i < 4; ++i) { int tv = wsum[i]; wsum[i] = r; r += tv; }
  }
  __syncthreads();
  return x - v + wsum[w];
}

__device__ __forceinline__ int excl_scan_512(int v, int* wsum) {
  int t = threadIdx.x, lane = t & 63, w = t >> 6;
  int x = v;
#pragma unroll
  for (int off = 1; off < 64; off <<= 1) {
    int y = __shfl_up(x, off, 64);
    if (lane >= off) x += y;
  }
  if (lane == 63) wsum[w] = x;
  __syncthreads();
  if (t == 0) {
    int r = 0;
#pragma unroll
    for (int i = 0; i < 8; ++i) { int tv = wsum[i]; wsum[i] = r; r += tv; }
  }
  __syncthreads();
  return x - v + wsum[w];
}

// ---------- pass 1: per-block coarse histogram (LDS atomics only) ----------
__global__ void k_hist(const int* __restrict__ dst, int* __restrict__ bhist) {
  __shared__ int hist[NBUCK];
  int t = threadIdx.x, k = blockIdx.x;
  for (int b = t; b < NBUCK; b += 256) hist[b] = 0;
  __syncthreads();
  int e0 = k * CHUNK, e1 = e0 + CHUNK;
  for (int e = e0 + t; e < e1; e += 256) atomicAdd(&hist[dst[e] >> 8], 1);
  __syncthreads();
  for (int b = t; b < NBUCK; b += 256) bhist[b * NBLK + k] = hist[b];
}

// ---------- pass 2a: scan each bucket's per-block counts + graph bounds ----
__global__ void k_scan_a(const int* __restrict__ bhist, int* __restrict__ boffl,
                         int* __restrict__ bsum, const int* __restrict__ batch,
                         int* __restrict__ gstart) {
  __shared__ int wsum[4];
  int t = threadIdx.x, b = blockIdx.x;
  int i = b * 256 + t;
  if (i < N_NODES) {
    int bi = batch[i];
    if (i == 0) {
      for (int g = 0; g <= bi; ++g) gstart[g] = 0;
    } else {
      int bp = batch[i - 1];
      for (int g = bp + 1; g <= bi; ++g) gstart[g] = i;
    }
    if (i == N_NODES - 1) {
      for (int g = bi + 1; g <= N_GRAPHS; ++g) gstart[g] = N_NODES;
    }
  }
  int v = bhist[b * NBLK + t];
  int ex = excl_scan_256(v, wsum);
  boffl[b * NBLK + t] = ex;
  if (t == NBLK - 1) bsum[b] = ex + v;
}

// ---------- pass 2b: scan bucket totals -> bstart; zero pooled output ------
__global__ void k_scan_b(const int* __restrict__ bsum, int* __restrict__ bstart,
                         float* __restrict__ pooled) {
  __shared__ int wsum[8];
  int t = threadIdx.x;
  for (int i = t; i < N_GRAPHS * 32; i += 512) pooled[i] = 0.f;
  int v = (t < NBUCK) ? bsum[t] : 0;
  int ex = excl_scan_512(v, wsum);
  if (t <= NBUCK) bstart[t] = ex;
}

// ---------- pass 3: scatter edges into coarse buckets (LDS atomics only) ----
__global__ void k_scatter(const int* __restrict__ src, const int* __restrict__ dst,
                          const int* __restrict__ bstart, const int* __restrict__ boffl,
                          int* __restrict__ tmp) {
  __shared__ int sbase[NBUCK];
  __shared__ int fill[NBUCK];
  int t = threadIdx.x, k = blockIdx.x;
  for (int b = t; b < NBUCK; b += 256) {
    sbase[b] = bstart[b] + boffl[b * NBLK + k];
    fill[b] = 0;
  }
  __syncthreads();
  int e0 = k * CHUNK, e1 = e0 + CHUNK;
  for (int e = e0 + t; e < e1; e += 256) {
    int s_ = src[e], d_ = dst[e];
    int b = d_ >> 8;
    int pos = sbase[b] + atomicAdd(&fill[b], 1);
    tmp[pos] = (s_ << 8) | (d_ & 255);
  }
}

// ---------- pass 4: per-bucket fine CSR + dis + s (LDS atomics only) -------
__global__ void k_fine(const int* __restrict__ tmp, const int* __restrict__ bstart,
                       const float* __restrict__ x, int* __restrict__ csr_src,
                       int* __restrict__ row_ptr, float* __restrict__ dis,
                       float2* __restrict__ s) {
  __shared__ int hist[256];   // becomes scanned offsets after scan
  __shared__ int fill[256];
  __shared__ int wsum[4];
  int t = threadIdx.x, b = blockIdx.x;
  int base_n = b << 8;
  int e0 = bstart[b], e1 = bstart[b + 1];
  hist[t] = 0;
  __syncthreads();
  for (int e = e0 + t; e < e1; e += 256) atomicAdd(&hist[tmp[e] & 255], 1);
  __syncthreads();
  int h = hist[t];
  int ex = excl_scan_256(h, wsum);
  hist[t] = ex;
  fill[t] = 0;
  int nn = min(256, N_NODES - base_n);
  if (t < nn) {
    int v = base_n + t;
    row_ptr[v] = e0 + ex;
    float dv = rsqrtf((float)(h + 1));
    dis[v] = dv;
    float2 xv = ((const float2*)x)[v];
    s[v] = make_float2(xv.x * dv, xv.y * dv);
  }
  if (b == NBUCK - 1 && t == 0) row_ptr[N_NODES] = e1;
  __syncthreads();
  for (int e = e0 + t; e < e1; e += 256) {
    int p = tmp[e];
    int fine = p & 255;
    int pos = e0 + hist[fine] + atomicAdd(&fill[fine], 1);
    csr_src[pos] = p >> 8;
  }
}

// ---------- layer 1 fused: t = dis*(sum s + self); q = fp16(dis*relu(t@W1+b1)@W2)
// Weights read straight from global at wave-uniform addresses -> scalar loads
// (s_load into SGPRs, off the LDS pipe). No LDS in this kernel.
__global__ void k_layer1(const float2* __restrict__ s, const float* __restrict__ dis,
                         const int* __restrict__ row_ptr, const int* __restrict__ csr_src,
                         const float* __restrict__ W1, const float* __restrict__ b1,
                         const float* __restrict__ W2, int4* __restrict__ q_lo,
                         int4* __restrict__ q_hi) {
  int v = blockIdx.x * 256 + threadIdx.x;
  if (v >= N_NODES) return;
  int beg = row_ptr[v], end = row_ptr[v + 1];
  float2 sv = s[v];
  float t0 = sv.x, t1 = sv.y;
  int k = beg;
  for (; k + 4 <= end; k += 4) {
    int u0 = csr_src[k], u1 = csr_src[k + 1], u2 = csr_src[k + 2], u3 = csr_src[k + 3];
    float2 a = s[u0], b = s[u1], c = s[u2], d = s[u3];
    t0 += (a.x + b.x) + (c.x + d.x);
    t1 += (a.y + b.y) + (c.y + d.y);
  }
  for (; k < end; ++k) {
    float2 su = s[csr_src[k]];
    t0 += su.x;
    t1 += su.y;
  }
  float dv = dis[v];
  t0 *= dv;
  t1 *= dv;
  float acc[32];
#pragma unroll
  for (int m = 0; m < 32; ++m) acc[m] = 0.f;
#pragma unroll 4
  for (int j = 0; j < 64; ++j) {
    float r = fmaxf(fmaf(t0, W1[j], fmaf(t1, W1[64 + j], b1[j])), 0.f);
#pragma unroll
    for (int m = 0; m < 32; ++m) acc[m] = fmaf(r, W2[j * 32 + m], acc[m]);
  }
  int pk[16];
#pragma unroll
  for (int m = 0; m < 16; ++m) {
    __half2 h = __floats2half2_rn(acc[2 * m] * dv, acc[2 * m + 1] * dv);
    pk[m] = *reinterpret_cast<int*>(&h);
  }
  q_lo[v * 2]     = make_int4(pk[0], pk[1], pk[2], pk[3]);
  q_lo[v * 2 + 1] = make_int4(pk[4], pk[5], pk[6], pk[7]);
  q_hi[v * 2]     = make_int4(pk[8], pk[9], pk[10], pk[11]);
  q_hi[v * 2 + 1] = make_int4(pk[12], pk[13], pk[14], pk[15]);
}

// ---------- layer 2 + pooling, XCD-partitioned feature halves --------------
// wg w: half = (w&7)>>2 (XCDs 0-3 -> lo plane, 4-7 -> hi plane);
// sub-block (w>>3)*4+(w&3) covers 64 nodes. 4 lanes per node-row, each lane
// owns 4 features read as one dwordx2 (2x half2); 1 node per rowgroup.
__device__ __forceinline__ float4 qunpack(uint2 p) {
  __half2 h0 = *reinterpret_cast<__half2*>(&p.x);
  __half2 h1 = *reinterpret_cast<__half2*>(&p.y);
  float2 a = __half22float2(h0), b = __half22float2(h1);
  return make_float4(a.x, a.y, b.x, b.y);
}

__global__ void k_layer2(const uint2* __restrict__ q_lo, const uint2* __restrict__ q_hi,
                         const float* __restrict__ dis, const int* __restrict__ row_ptr,
                         const int* __restrict__ csr_src, const int* __restrict__ batch,
                         float* __restrict__ pooled) {
  __shared__ float4 red[64][4];
  int w = blockIdx.x;
  int h = (w & 7) >> 2;
  int sub = (w >> 3) * 4 + (w & 3);
  if (sub >= NODEBLK) return;
  const uint2* q = h ? q_hi : q_lo;
  int t = threadIdx.x;
  int fp = t & 3;           // feature quad 0..3
  int rg = t >> 2;          // node within block 0..63
  int vb = sub * 64;
  int v = vb + rg;
  int nlast = min(vb + 63, N_NODES - 1);
  bool uniform = (batch[vb] == batch[nlast]);
  float4 acc = make_float4(0.f, 0.f, 0.f, 0.f);
  int g = -1;
  if (v < N_NODES) {
    g = batch[v];
    int e0 = row_ptr[v], e1 = row_ptr[v + 1];
    float4 z = qunpack(q[v * 4 + fp]);
    int k = e0;
    for (; k + 8 <= e1; k += 8) {
      int u0 = csr_src[k],     u1 = csr_src[k + 1], u2 = csr_src[k + 2], u3 = csr_src[k + 3];
      int u4 = csr_src[k + 4], u5 = csr_src[k + 5], u6 = csr_src[k + 6], u7 = csr_src[k + 7];
      float4 f0 = qunpack(q[u0 * 4 + fp]);
      float4 f1 = qunpack(q[u1 * 4 + fp]);
      float4 f2 = qunpack(q[u2 * 4 + fp]);
      float4 f3 = qunpack(q[u3 * 4 + fp]);
      float4 f4 = qunpack(q[u4 * 4 + fp]);
      float4 f5 = qunpack(q[u5 * 4 + fp]);
      float4 f6 = qunpack(q[u6 * 4 + fp]);
      float4 f7 = qunpack(q[u7 * 4 + fp]);
      z.x += ((f0.x + f1.x) + (f2.x + f3.x)) + ((f4.x + f5.x) + (f6.x + f7.x));
      z.y += ((f0.y + f1.y) + (f2.y + f3.y)) + ((f4.y + f5.y) + (f6.y + f7.y));
      z.z += ((f0.z + f1.z) + (f2.z + f3.z)) + ((f4.z + f5.z) + (f6.z + f7.z));
      z.w += ((f0.w + f1.w) + (f2.w + f3.w)) + ((f4.w + f5.w) + (f6.w + f7.w));
    }
    for (; k + 2 <= e1; k += 2) {
      int u0 = csr_src[k], u1 = csr_src[k + 1];
      float4 f0 = qunpack(q[u0 * 4 + fp]);
      float4 f1 = qunpack(q[u1 * 4 + fp]);
      z.x += f0.x + f1.x;
      z.y += f0.y + f1.y;
      z.z += f0.z + f1.z;
      z.w += f0.w + f1.w;
    }
    for (; k < e1; ++k) {
      float4 f = qunpack(q[csr_src[k] * 4 + fp]);
      z.x += f.x; z.y += f.y; z.z += f.z; z.w += f.w;
    }
    float dvv = dis[v];
    acc = make_float4(z.x * dvv, z.y * dvv, z.z * dvv, z.w * dvv);
  }
  if (uniform) {
    red[rg][fp] = acc;
    __syncthreads();
    if (t < 4) {
      float4 ssum = make_float4(0.f, 0.f, 0.f, 0.f);
#pragma unroll
      for (int r = 0; r < 64; ++r) {
        float4 x4 = red[r][t];
        ssum.x += x4.x; ssum.y += x4.y; ssum.z += x4.z; ssum.w += x4.w;
      }
      int gg = batch[vb];
      int base = gg * 32 + h * 16 + t * 4;
      atomicAdd(&pooled[base],     ssum.x);
      atomicAdd(&pooled[base + 1], ssum.y);
      atomicAdd(&pooled[base + 2], ssum.z);
      atomicAdd(&pooled[base + 3], ssum.w);
    }
  } else if (v < N_NODES) {
    int base = g * 32 + h * 16 + fp * 4;
    atomicAdd(&pooled[base],     acc.x);
    atomicAdd(&pooled[base + 1], acc.y);
    atomicAdd(&pooled[base + 2], acc.z);
    atomicAdd(&pooled[base + 3], acc.w);
  }
}

// ---------- final: mean + b2 ----------
__global__ void k_final(float* __restrict__ out, const int* __restrict__ gstart,
                        const float* __restrict__ b2) {
  int i = blockIdx.x * 256 + threadIdx.x;
  if (i < N_GRAPHS * 32) {
    int g = i >> 5, l = i & 31;
    int c = gstart[g + 1] - gstart[g];
    out[i] = (c > 0) ? out[i] / (float)c + b2[l] : 0.f;
  }
}

extern "C" void kernel_launch(void* const* d_in, const int* in_sizes, int n_in,
                              void* d_out, int out_size, void* d_ws, size_t ws_size,
                              hipStream_t stream) {
  (void)in_sizes; (void)n_in; (void)out_size; (void)ws_size;
  const float* x   = (const float*)d_in[0];
  const float* W1  = (const float*)d_in[1];
  const float* b1  = (const float*)d_in[2];
  const float* W2  = (const float*)d_in[3];
  const float* b2  = (const float*)d_in[4];
  const int* edge  = (const int*)d_in[5];
  const int* batch = (const int*)d_in[6];
  const int* src = edge;             // edge_index[0]
  const int* dst = edge + N_EDGES;   // edge_index[1]
  float* out = (float*)d_out;

  int* ws      = (int*)d_ws;
  int* gstart  = ws + OFF_GSTART;
  int* row_ptr = ws + OFF_ROWPTR;
  float* dis   = (float*)(ws + OFF_DIS);
  float2* s    = (float2*)(ws + OFF_S);
  int* csr_src = ws + OFF_CSR;
  int4* q_lo4  = (int4*)(ws + OFF_QLO);
  int4* q_hi4  = (int4*)(ws + OFF_QHI);
  int* bhist   = ws + OFF_BHIST;
  int* boffl   = ws + OFF_BOFFL;
  int* bsum    = ws + OFF_BSUM;
  int* bstart  = ws + OFF_BSTART;
  int* tmp     = ws + OFF_TMP;

  k_hist<<<NBLK, 256, 0, stream>>>(dst, bhist);
  k_scan_a<<<NBUCK, 256, 0, stream>>>(bhist, boffl, bsum, batch, gstart);
  k_scan_b<<<1, 512, 0, stream>>>(bsum, bstart, out);
  k_scatter<<<NBLK, 256, 0, stream>>>(src, dst, bstart, boffl, tmp);
  k_fine<<<NBUCK, 256, 0, stream>>>(tmp, bstart, x, csr_src, row_ptr, dis, s);
  k_layer1<<<(N_NODES + 255) / 256, 256, 0, stream>>>(s, dis, row_ptr, csr_src,
                                                      W1, b1, W2, q_lo4, q_hi4);
  const int n_wg2 = ((NODEBLK + 3) / 4) * 8;   // 3128
  k_layer2<<<n_wg2, 256, 0, stream>>>((const uint2*)q_lo4, (const uint2*)q_hi4,
                                      dis, row_ptr, csr_src, batch, out);
  k_final<<<8, 256, 0, stream>>>(out, gstart, b2);
}